// Round 17
// baseline (203.619 us; speedup 1.0000x reference)
//
#include <hip/hip_runtime.h>
#include <stdint.h>

#define B_ 8
#define N_ 1024
#define C_ 768
#define H_ 12
#define G_ 6
#define QBLK 64
#define KSTEP 64
#define NQT 16   // 1024/64
#define NKS 16   // 1024/64

typedef __attribute__((ext_vector_type(8))) short bf16x8;
typedef __attribute__((ext_vector_type(8))) unsigned short u16x8;
typedef __attribute__((ext_vector_type(4))) float f32x4;

__device__ __forceinline__ float bf2f(unsigned short u) {
  return __uint_as_float(((unsigned)u) << 16);
}
// float -> bf16 (RNE) via hardware cast (compiler emits v_cvt_pk_bf16_f32).
__device__ __forceinline__ unsigned short f2bf(float f) {
  __bf16 b = (__bf16)f;
  unsigned short u;
  __builtin_memcpy(&u, &b, 2);
  return u;
}
__device__ __forceinline__ void gload16(const void* g, void* l) {
  __builtin_amdgcn_global_load_lds(
      (const __attribute__((address_space(1))) unsigned int*)g,
      (__attribute__((address_space(3))) unsigned int*)l, 16, 0, 0);
}

// ---------------- fp32 -> bf16 conversion (X and W merged) -----------------
__global__ __launch_bounds__(256) void cvtAll(
    const float* __restrict__ q, const float* __restrict__ k,
    const float* __restrict__ v, const float* __restrict__ wq,
    const float* __restrict__ wk, const float* __restrict__ wv,
    const float* __restrict__ wo, unsigned short* __restrict__ Xb,
    unsigned short* __restrict__ Wb) {
  const int bi = blockIdx.x;
  const float* src;
  unsigned short* d;
  size_t base;
  if (bi < 9216) {
    const int t = bi / 3072;
    src = (t == 0) ? q : (t == 1) ? k : v;
    d = Xb + (size_t)t * ((size_t)B_ * N_ * C_);
    base = (size_t)(bi % 3072) * 2048;
  } else {
    const int t = (bi - 9216) / 288;
    src = (t == 0) ? wq : (t == 1) ? wk : (t == 2) ? wv : wo;
    d = Wb + (size_t)t * ((size_t)C_ * C_);
    base = (size_t)((bi - 9216) % 288) * 2048;
  }
  const size_t idx = base + (size_t)threadIdx.x * 8;
  const float4 f0 = *(const float4*)(src + idx);
  const float4 f1 = *(const float4*)(src + idx + 4);
  u16x8 o;
  o[0] = f2bf(f0.x); o[1] = f2bf(f0.y); o[2] = f2bf(f0.z); o[3] = f2bf(f0.w);
  o[4] = f2bf(f1.x); o[5] = f2bf(f1.y); o[6] = f2bf(f1.z); o[7] = f2bf(f1.w);
  *(u16x8*)(d + idx) = o;
}

// ======= bf16 MFMA GEMM (m97-style global_load_lds staging) ================
template <int MODE>
__device__ __forceinline__ void gemm_bf16(
    const unsigned short* __restrict__ X, const unsigned short* __restrict__ W,
    const float* __restrict__ bias, void* __restrict__ out, int row0, int col0,
    unsigned short* __restrict__ As, unsigned short* __restrict__ Bs) {
  const int tid = threadIdx.x;
  const int wid = tid >> 6, lane = tid & 63;
  const int lr = lane & 15, lk = (lane >> 4) << 3;
  const int qrow = (lane >> 4) << 2;
  const int wr = (wid & 1) << 6, wc = (wid >> 1) << 6;
  const int srow = (wid << 4) + (lane >> 2);
  const int scol = (lane & 3) << 3;
  const unsigned short* gA0 = X + (size_t)(row0 + srow) * C_ + scol;
  const unsigned short* gA1 = X + (size_t)(row0 + 64 + srow) * C_ + scol;
  const unsigned short* gB0 = W + (size_t)(col0 + srow) * C_ + scol;
  const unsigned short* gB1 = W + (size_t)(col0 + 64 + srow) * C_ + scol;
  unsigned short* lA0 = As + (wid << 9);
  unsigned short* lA1 = As + 2048 + (wid << 9);
  unsigned short* lB0 = Bs + (wid << 9);
  unsigned short* lB1 = Bs + 2048 + (wid << 9);
  f32x4 acc[4][4] = {};
  for (int k0 = 0; k0 < C_; k0 += 32) {
    gload16(gA0 + k0, lA0);
    gload16(gA1 + k0, lA1);
    gload16(gB0 + k0, lB0);
    gload16(gB1 + k0, lB1);
    __syncthreads();
    bf16x8 af[4], bg[4];
#pragma unroll
    for (int m = 0; m < 4; ++m)
      af[m] = *(const bf16x8*)&As[(wr + (m << 4) + lr) * 32 + lk];
#pragma unroll
    for (int n = 0; n < 4; ++n)
      bg[n] = *(const bf16x8*)&Bs[(wc + (n << 4) + lr) * 32 + lk];
#pragma unroll
    for (int m = 0; m < 4; ++m)
#pragma unroll
      for (int n = 0; n < 4; ++n)
        acc[m][n] = __builtin_amdgcn_mfma_f32_16x16x32_bf16(af[m], bg[n],
                                                            acc[m][n], 0, 0, 0);
    __syncthreads();
  }
#pragma unroll
  for (int m = 0; m < 4; ++m) {
#pragma unroll
    for (int n = 0; n < 4; ++n) {
      const int colc = col0 + wc + (n << 4) + lr;
      const float bv = bias[colc];
      if (MODE == 2) {
        const int r0 = row0 + wr + (m << 4) + qrow;
        const int bb = r0 >> 10, nn0 = r0 & 1023;
        const int hh = colc >> 6, dd = colc & 63;
        ushort4 pk;
        pk.x = f2bf(acc[m][n][0] + bv);
        pk.y = f2bf(acc[m][n][1] + bv);
        pk.z = f2bf(acc[m][n][2] + bv);
        pk.w = f2bf(acc[m][n][3] + bv);
        *(ushort4*)&((unsigned short*)out)[(((size_t)(bb * H_ + hh) << 6) + dd)
                                               * 1024 + nn0] = pk;
      } else {
#pragma unroll
        for (int q = 0; q < 4; ++q) {
          const int r = row0 + wr + (m << 4) + qrow + q;
          const float v = acc[m][n][q] + bv;
          if (MODE == 0) {
            ((float*)out)[(size_t)r * C_ + colc] = v;
          } else {
            const int bb = r >> 10, nn = r & 1023;
            const int hh = colc >> 6, dd = colc & 63;
            ((unsigned short*)out)[(((size_t)(bb * H_ + hh) << 10) + nn) * 64 +
                                   dd] = f2bf(v);
          }
        }
      }
    }
  }
}

__global__ __launch_bounds__(256) void proj3(
    const unsigned short* __restrict__ Xb, const unsigned short* __restrict__ Wb,
    const float* __restrict__ bq, const float* __restrict__ bk,
    const float* __restrict__ bv, unsigned short* Qb, unsigned short* Kb,
    unsigned short* Vt) {
  __shared__ __align__(16) unsigned short As[128 * 32];
  __shared__ __align__(16) unsigned short Bs[128 * 32];
  const int wg = blockIdx.x;
  const int nid = (wg & 7) * 144 + (wg >> 3);
  const int x = nid % 6, y = (nid / 6) & 63, z = nid / 384;
  const unsigned short* X = Xb + (size_t)z * B_ * N_ * C_;
  const unsigned short* W = Wb + (size_t)z * C_ * C_;
  if (z == 0)
    gemm_bf16<1>(X, W, bq, Qb, y << 7, x << 7, As, Bs);
  else if (z == 1)
    gemm_bf16<1>(X, W, bk, Kb, y << 7, x << 7, As, Bs);
  else
    gemm_bf16<2>(X, W, bv, Vt, y << 7, x << 7, As, Bs);
}

__global__ __launch_bounds__(256) void oproj(
    const unsigned short* __restrict__ X, const unsigned short* __restrict__ Wb,
    const float* __restrict__ bo, float* __restrict__ out) {
  __shared__ __align__(16) unsigned short As[128 * 32];
  __shared__ __align__(16) unsigned short Bs[128 * 32];
  const int wg = blockIdx.x;
  const int nid = (wg & 7) * 48 + (wg >> 3);
  const int x = nid % 6, y = nid / 6;
  gemm_bf16<0>(X, Wb + (size_t)3 * C_ * C_, bo, out, y << 7, x << 7, As, Bs);
}

// ============ fused: conv-folded QK^T (swapped) -> reg softmax -> PV =======
// QBLK=64, 4 waves (h, mt), 2 q-subtiles per wave. LDS trimmed to 43,008 B
// (K 16896 + V 16384 + Pt 9216 + lsum 512) so 3 blocks/CU fit and the
// 768-block grid runs in ONE residency round (no tail).
// Q for qtf read directly from global (once). Phase 4+5 run per-qs so the
// per-wave Pt buffer [16][72] is reused sequentially.
__global__ __launch_bounds__(256, 2) void fused_attn(
    const unsigned short* __restrict__ Qb, const unsigned short* __restrict__ Kb,
    const unsigned short* __restrict__ Vt, const float* __restrict__ cw,
    const float* __restrict__ hm, unsigned short* __restrict__ pvout) {
  __shared__ __align__(16) unsigned char smem[43008];
  float* lsum = (float*)(smem + 42496);  // [h][row] = lsum[h*64+row]
#define KBASE(hh) (smem + (size_t)(hh)*8448)
#define VBASE(hh) (smem + 16896 + (size_t)(hh)*8192)

  const int wg = blockIdx.x;  // 768 = 8 * 96
  const int nid = (wg & 7) * 96 + (wg >> 3);
  const int qt = nid & 15;
  const int bg = nid >> 4;
  const int g = bg % G_, bb = bg / G_;
  const int i0 = qt << 6;

  const int tid = threadIdx.x;
  const int wid = tid >> 6, lane = tid & 63;
  const int lr = lane & 15, lg = lane >> 4;
  const int lk = lg << 3;

  const int h = wid >> 1, mt = wid & 1;  // wave role: (head, 32-row q-half)

  const size_t HSTR = (size_t)N_ * 64;
  const unsigned short* Qz = Qb + (size_t)(bb * H_ + 2 * g) * HSTR;
  const unsigned short* Kz = Kb + (size_t)(bb * H_ + 2 * g) * HSTR;
  const unsigned short* Vz = Vt + (size_t)(bb * H_ + 2 * g) * HSTR;  // [h][d][n]

  // staging roles (KSTEP only)
  const int krow = tid >> 2, kd0 = (tid & 3) << 4;        // K rows 0..63
  const int kc0 = (tid & 3) << 1;                         // 16B chunks 0,2,4,6
  const int k2r = 64 + (tid >> 3), k2d = (tid & 7) << 3;  // halo rows (tid<16)
  const int vd = tid >> 2, vc0 = (tid & 3) << 4;          // V^T rows

  u16x8 kreg[4], vreg[4];
  u16x8 kreg2[2];

  // ---- prefetch step 0 ----
  {
    const int gj = -1 + krow;
#pragma unroll
    for (int hh = 0; hh < 2; ++hh) {
      u16x8 a = {}, b = {};
      if (gj >= 0) {
        a = *(const u16x8*)(Kz + hh * HSTR + (size_t)gj * 64 + kd0);
        b = *(const u16x8*)(Kz + hh * HSTR + (size_t)gj * 64 + kd0 + 8);
      }
      kreg[2 * hh] = a; kreg[2 * hh + 1] = b;
    }
    if (tid < 16) {
      const int gj2 = -1 + k2r;  // 63 or 64
#pragma unroll
      for (int hh = 0; hh < 2; ++hh)
        kreg2[hh] = *(const u16x8*)(Kz + hh * HSTR + (size_t)gj2 * 64 + k2d);
    }
#pragma unroll
    for (int hh = 0; hh < 2; ++hh)
#pragma unroll
      for (int hf = 0; hf < 2; ++hf)
        vreg[2 * hh + hf] =
            *(const u16x8*)(Vz + hh * HSTR + (size_t)vd * 1024 + vc0 + (hf << 3));
  }

  // ---- qtf directly from global Q (12 guarded 16B loads, once) ----
  // weights folded: *0.125 (1/sqrt(D)) and *log2(e) (exp2 domain)
  bf16x8 qtf[2][3][2];  // [qs][c][dh]
  {
    float wc3[3][3];
#pragma unroll
    for (int a = 0; a < 3; ++a)
#pragma unroll
      for (int c = 0; c < 3; ++c)
        wc3[a][c] = cw[(2 * g + h) * 9 + a * 3 + c] *
                    (0.125f * 1.4426950408889634f);
#pragma unroll
    for (int qs = 0; qs < 2; ++qs) {
      const int ribase = (mt << 5) + (qs << 4) + lr;
      u16x8 qrows[3][2];
#pragma unroll
      for (int a = 0; a < 3; ++a) {
        const int gi = i0 + ribase - 1 + a;
        const bool ok = ((unsigned)gi < (unsigned)N_);
#pragma unroll
        for (int dh = 0; dh < 2; ++dh) {
          u16x8 qv = {};
          if (ok)
            qv = *(const u16x8*)(Qz + h * HSTR + (size_t)gi * 64 + (dh << 5) + lk);
          qrows[a][dh] = qv;
        }
      }
#pragma unroll
      for (int c = 0; c < 3; ++c)
#pragma unroll
        for (int dh = 0; dh < 2; ++dh)
#pragma unroll
          for (int e = 0; e < 8; ++e) {
            const float v = bf2f(qrows[0][dh][e]) * wc3[0][c] +
                            bf2f(qrows[1][dh][e]) * wc3[1][c] +
                            bf2f(qrows[2][dh][e]) * wc3[2][c];
            qtf[qs][c][dh][e] = (short)f2bf(v);
          }
    }
  }

  unsigned short* PtW =
      (unsigned short*)(smem + 33280) + (size_t)wid * 1152;  // [16][72] u16

  // precomputed swizzled read offsets (row&7 = (lr+c)&7 for K, lr&7 for V)
  const unsigned char* kbB = KBASE(h) + lr * 128;
  int kofs[3][2];
#pragma unroll
  for (int c = 0; c < 3; ++c)
#pragma unroll
    for (int dh = 0; dh < 2; ++dh)
      kofs[c][dh] = (((((dh << 2) + lg) ^ ((lr + c) & 7)) << 4)) + c * 128;
  const unsigned char* vbB0 = VBASE(0) + lr * 128;
  const unsigned char* vbB1 = VBASE(1) + lr * 128;
  int vofs[2];
#pragma unroll
  for (int kj = 0; kj < 2; ++kj)
    vofs[kj] = ((((kj << 2) + lg) ^ (lr & 7)) << 4);

  float mreg[2] = {-3.0e38f, -3.0e38f};
  float lreg[2] = {0.f, 0.f};
  f32x4 acc[2][2][4] = {};  // [v-head k2][qs][nt(d)]

  for (int s = 0; s < NKS; ++s) {
    // ---- phase 1: write staged K/V regs to LDS (swizzled chunks) ----
    {
      unsigned char* kr0 = KBASE(0) + krow * 128;
      unsigned char* kr1 = KBASE(1) + krow * 128;
      const int ksw = krow & 7;
      *(u16x8*)(kr0 + ((kc0 ^ ksw) << 4)) = kreg[0];
      *(u16x8*)(kr0 + (((kc0 + 1) ^ ksw) << 4)) = kreg[1];
      *(u16x8*)(kr1 + ((kc0 ^ ksw) << 4)) = kreg[2];
      *(u16x8*)(kr1 + (((kc0 + 1) ^ ksw) << 4)) = kreg[3];
      if (tid < 16) {
        const int k2sw = k2r & 7, k2c = tid & 7;
        *(u16x8*)(KBASE(0) + k2r * 128 + ((k2c ^ k2sw) << 4)) = kreg2[0];
        *(u16x8*)(KBASE(1) + k2r * 128 + ((k2c ^ k2sw) << 4)) = kreg2[1];
      }
      unsigned char* vr0 = VBASE(0) + vd * 128;
      unsigned char* vr1 = VBASE(1) + vd * 128;
      const int vsw = vd & 7, vcc = (tid & 3) << 1;
      *(u16x8*)(vr0 + ((vcc ^ vsw) << 4)) = vreg[0];
      *(u16x8*)(vr0 + (((vcc + 1) ^ vsw) << 4)) = vreg[1];
      *(u16x8*)(vr1 + ((vcc ^ vsw) << 4)) = vreg[2];
      *(u16x8*)(vr1 + (((vcc + 1) ^ vsw) << 4)) = vreg[3];
    }
    __syncthreads();  // B1

    // ---- phase 2: issue loads for step s+1 ----
    if (s + 1 < NKS) {
      const int j1 = (s + 1) << 6;
      const int gj = j1 - 1 + krow;
#pragma unroll
      for (int hh = 0; hh < 2; ++hh) {
        kreg[2 * hh] = *(const u16x8*)(Kz + hh * HSTR + (size_t)gj * 64 + kd0);
        kreg[2 * hh + 1] =
            *(const u16x8*)(Kz + hh * HSTR + (size_t)gj * 64 + kd0 + 8);
      }
      if (tid < 16) {
        const int gj2 = j1 - 1 + k2r;
#pragma unroll
        for (int hh = 0; hh < 2; ++hh) {
          u16x8 a = {};
          if (gj2 < N_)
            a = *(const u16x8*)(Kz + hh * HSTR + (size_t)gj2 * 64 + k2d);
          kreg2[hh] = a;
        }
      }
#pragma unroll
      for (int hh = 0; hh < 2; ++hh)
#pragma unroll
        for (int hf = 0; hf < 2; ++hf)
          vreg[2 * hh + hf] = *(const u16x8*)(Vz + hh * HSTR + (size_t)vd * 1024 +
                                              j1 + vc0 + (hf << 3));
    }

    // ---- phase 3: swapped conv-QK^T, K-frag shared across both qs ----
    f32x4 racc[2][4] = {};
    __builtin_amdgcn_s_setprio(1);
#pragma unroll
    for (int c = 0; c < 3; ++c) {
#pragma unroll
      for (int dh = 0; dh < 2; ++dh) {
#pragma unroll
        for (int nt = 0; nt < 4; ++nt) {
          const bf16x8 ak = *(const bf16x8*)(kbB + nt * 2048 + kofs[c][dh]);
          racc[0][nt] = __builtin_amdgcn_mfma_f32_16x16x32_bf16(
              ak, qtf[0][c][dh], racc[0][nt], 0, 0, 0);
          racc[1][nt] = __builtin_amdgcn_mfma_f32_16x16x32_bf16(
              ak, qtf[1][c][dh], racc[1][nt], 0, 0, 0);
        }
      }
    }
    __builtin_amdgcn_s_setprio(0);

    // ---- phase 4: softmax max + (rare) rescale, both qs ----
    {
      float pmax[2];
#pragma unroll
      for (int qs = 0; qs < 2; ++qs) {
        float pm = fmaxf(fmaxf(racc[qs][0][0], racc[qs][0][1]),
                         fmaxf(racc[qs][0][2], racc[qs][0][3]));
#pragma unroll
        for (int nt = 1; nt < 4; ++nt)
          pm = fmaxf(pm, fmaxf(fmaxf(racc[qs][nt][0], racc[qs][nt][1]),
                               fmaxf(racc[qs][nt][2], racc[qs][nt][3])));
        pm = fmaxf(pm, __shfl_xor(pm, 16));
        pm = fmaxf(pm, __shfl_xor(pm, 32));
        pmax[qs] = pm;
      }
      if (__any((pmax[0] > mreg[0] + 8.f) || (pmax[1] > mreg[1] + 8.f))) {
#pragma unroll
        for (int qs = 0; qs < 2; ++qs) {
          const float mn = fmaxf(mreg[qs], pmax[qs]);
          const float alpha = exp2f(mreg[qs] - mn);
          mreg[qs] = mn;
          lreg[qs] *= alpha;
          float a4[4];
#pragma unroll
          for (int q = 0; q < 4; ++q)
            a4[q] = __shfl(alpha, (lg << 4) | ((lg << 2) + q));
#pragma unroll
          for (int k2 = 0; k2 < 2; ++k2)
#pragma unroll
            for (int nt = 0; nt < 4; ++nt)
#pragma unroll
              for (int q = 0; q < 4; ++q) acc[k2][qs][nt][q] *= a4[q];
        }
      }
      // ---- phases 4b+5 per q-subtile: exp2 + pack -> Pt -> PV ----
#pragma unroll
      for (int qs = 0; qs < 2; ++qs) {
        float rs = 0.f;
#pragma unroll
        for (int nt = 0; nt < 4; ++nt)
#pragma unroll
          for (int q = 0; q < 4; ++q) {
            const float p = exp2f(racc[qs][nt][q] - mreg[qs]);
            racc[qs][nt][q] = p;
            rs += p;
          }
        rs += __shfl_xor(rs, 16);
        rs += __shfl_xor(rs, 32);
        lreg[qs] += rs;
#pragma unroll
        for (int nt = 0; nt < 4; ++nt) {
          ushort4 pw;
          pw.x = f2bf(racc[qs][nt][0]); pw.y = f2bf(racc[qs][nt][1]);
          pw.z = f2bf(racc[qs][nt][2]); pw.w = f2bf(racc[qs][nt][3]);
          *(ushort4*)&PtW[(size_t)lr * 72 + (nt << 4) + (lg << 2)] = pw;
        }
        bf16x8 paf[2];
        paf[0] = *(const bf16x8*)&PtW[(size_t)lr * 72 + lk];
        paf[1] = *(const bf16x8*)&PtW[(size_t)lr * 72 + 32 + lk];
        __builtin_amdgcn_s_setprio(1);
#pragma unroll
        for (int kj = 0; kj < 2; ++kj)
#pragma unroll
          for (int nt = 0; nt < 4; ++nt) {
            const bf16x8 bva = *(const bf16x8*)(vbB0 + nt * 2048 + vofs[kj]);
            const bf16x8 bvb = *(const bf16x8*)(vbB1 + nt * 2048 + vofs[kj]);
            acc[0][qs][nt] = __builtin_amdgcn_mfma_f32_16x16x32_bf16(
                paf[kj], bva, acc[0][qs][nt], 0, 0, 0);
            acc[1][qs][nt] = __builtin_amdgcn_mfma_f32_16x16x32_bf16(
                paf[kj], bvb, acc[1][qs][nt], 0, 0, 0);
          }
        __builtin_amdgcn_s_setprio(0);
      }
    }
    __syncthreads();  // B3 (protects K/V LDS for next staging)
  }

  // ---- epilogue: O_k = sum_h hm[h,k]/l_h * A_hk ----
  if (lg == 0) {
    lsum[h * 64 + (mt << 5) + lr] = lreg[0];
    lsum[h * 64 + (mt << 5) + 16 + lr] = lreg[1];
  }
  __syncthreads();

  const float mw0 = hm[(g * 2 + h) * 2 + 0];
  const float mw1 = hm[(g * 2 + h) * 2 + 1];
  float* Os = (float*)smem;  // [2k2][64 rows][68] f32 = 34,816 B (< lsum ofs)
  if (h == 1) {
#pragma unroll
    for (int qs = 0; qs < 2; ++qs)
#pragma unroll
      for (int q = 0; q < 4; ++q) {
        const int row = (mt << 5) + (qs << 4) + (lg << 2) + q;
        const float f0 = mw0 / lsum[64 + row];
        const float f1 = mw1 / lsum[64 + row];
#pragma unroll
        for (int nt = 0; nt < 4; ++nt) {
          Os[(size_t)(0 * 64 + row) * 68 + (nt << 4) + lr] =
              acc[0][qs][nt][q] * f0;
          Os[(size_t)(1 * 64 + row) * 68 + (nt << 4) + lr] =
              acc[1][qs][nt][q] * f1;
        }
      }
  }
  __syncthreads();
  if (h == 0) {
#pragma unroll
    for (int qs = 0; qs < 2; ++qs)
#pragma unroll
      for (int q = 0; q < 4; ++q) {
        const int row = (mt << 5) + (qs << 4) + (lg << 2) + q;
        const int gi = i0 + row;
        const float f0 = mw0 / lsum[row];
        const float f1 = mw1 / lsum[row];
#pragma unroll
        for (int nt = 0; nt < 4; ++nt) {
          const float v0 = acc[0][qs][nt][q] * f0 +
                           Os[(size_t)(0 * 64 + row) * 68 + (nt << 4) + lr];
          const float v1 = acc[1][qs][nt][q] * f1 +
                           Os[(size_t)(1 * 64 + row) * 68 + (nt << 4) + lr];
          pvout[(size_t)(bb * N_ + gi) * C_ + (2 * g + 0) * 64 + (nt << 4) +
                lr] = f2bf(v0);
          pvout[(size_t)(bb * N_ + gi) * C_ + (2 * g + 1) * 64 + (nt << 4) +
                lr] = f2bf(v1);
        }
      }
  }
#undef KBASE
#undef VBASE
}

extern "C" void kernel_launch(void* const* d_in, const int* in_sizes, int n_in,
                              void* d_out, int out_size, void* d_ws, size_t ws_size,
                              hipStream_t stream) {
  const float* query = (const float*)d_in[0];
  const float* key   = (const float*)d_in[1];
  const float* value = (const float*)d_in[2];
  const float* Wq = (const float*)d_in[3];
  const float* bq = (const float*)d_in[4];
  const float* Wk = (const float*)d_in[5];
  const float* bk = (const float*)d_in[6];
  const float* Wv = (const float*)d_in[7];
  const float* bv = (const float*)d_in[8];
  const float* cw = (const float*)d_in[9];
  const float* hm = (const float*)d_in[10];
  const float* Wo = (const float*)d_in[11];
  const float* bo = (const float*)d_in[12];
  float* out = (float*)d_out;

  char* ws = (char*)d_ws;
  const size_t SZ_BF = (size_t)B_ * H_ * N_ * 64 * 2;  // 12,582,912 B
  unsigned short* Qb = (unsigned short*)ws;
  unsigned short* Kb = (unsigned short*)(ws + SZ_BF);
  unsigned short* Vt = (unsigned short*)(ws + 2 * SZ_BF);   // (B,H,D,N)
  unsigned short* pvb = (unsigned short*)(ws + 3 * SZ_BF);  // bf16 (B,N,C)
  unsigned short* Xb = (unsigned short*)(ws + 4 * SZ_BF);   // q,k,v bf16
  unsigned short* Wb = (unsigned short*)(ws + 7 * SZ_BF);   // Wq,Wk,Wv,Wo bf16

  const dim3 blk(256);
  cvtAll<<<dim3(10368), blk, 0, stream>>>(query, key, value, Wq, Wk, Wv, Wo, Xb,
                                          Wb);
  proj3<<<dim3(1152), blk, 0, stream>>>(Xb, Wb, bq, bk, bv, Qb, Kb, Vt);
  fused_attn<<<dim3(768), blk, 0, stream>>>(Qb, Kb, Vt, cw, hm, pvb);
  oproj<<<dim3(384), blk, 0, stream>>>(pvb, Wb, bo, out);
}

// Round 18
// 177.611 us; speedup vs baseline: 1.1464x; 1.1464x over previous
//
#include <hip/hip_runtime.h>
#include <stdint.h>

#define B_ 8
#define N_ 1024
#define C_ 768
#define H_ 12
#define G_ 6
#define QBLK 64
#define KSTEP 64
#define NQT 16   // 1024/64
#define NKS 16   // 1024/64

typedef __attribute__((ext_vector_type(8))) short bf16x8;
typedef __attribute__((ext_vector_type(8))) unsigned short u16x8;
typedef __attribute__((ext_vector_type(4))) float f32x4;

__device__ __forceinline__ float bf2f(unsigned short u) {
  return __uint_as_float(((unsigned)u) << 16);
}
// float -> bf16 (RNE) via hardware cast (compiler emits v_cvt_pk_bf16_f32).
__device__ __forceinline__ unsigned short f2bf(float f) {
  __bf16 b = (__bf16)f;
  unsigned short u;
  __builtin_memcpy(&u, &b, 2);
  return u;
}
__device__ __forceinline__ void gload16(const void* g, void* l) {
  __builtin_amdgcn_global_load_lds(
      (const __attribute__((address_space(1))) unsigned int*)g,
      (__attribute__((address_space(3))) unsigned int*)l, 16, 0, 0);
}

// ---------------- fp32 -> bf16 conversion (streaming) ----------------------
__global__ __launch_bounds__(256) void cvtX(
    const float* __restrict__ q, const float* __restrict__ k,
    const float* __restrict__ v, unsigned short* __restrict__ dst) {
  const float* src = (blockIdx.y == 0) ? q : (blockIdx.y == 1) ? k : v;
  unsigned short* d = dst + (size_t)blockIdx.y * ((size_t)B_ * N_ * C_);
  const size_t idx = ((size_t)blockIdx.x * 256 + threadIdx.x) * 8;
  const float4 f0 = *(const float4*)(src + idx);
  const float4 f1 = *(const float4*)(src + idx + 4);
  u16x8 o;
  o[0] = f2bf(f0.x); o[1] = f2bf(f0.y); o[2] = f2bf(f0.z); o[3] = f2bf(f0.w);
  o[4] = f2bf(f1.x); o[5] = f2bf(f1.y); o[6] = f2bf(f1.z); o[7] = f2bf(f1.w);
  *(u16x8*)(d + idx) = o;
}

__global__ __launch_bounds__(256) void cvtW(
    const float* __restrict__ wq, const float* __restrict__ wk,
    const float* __restrict__ wv, const float* __restrict__ wo,
    unsigned short* __restrict__ dst) {
  const float* src = (blockIdx.y == 0)   ? wq
                     : (blockIdx.y == 1) ? wk
                     : (blockIdx.y == 2) ? wv
                                         : wo;
  unsigned short* d = dst + (size_t)blockIdx.y * ((size_t)C_ * C_);
  const size_t idx = ((size_t)blockIdx.x * 256 + threadIdx.x) * 8;
  const float4 f0 = *(const float4*)(src + idx);
  const float4 f1 = *(const float4*)(src + idx + 4);
  u16x8 o;
  o[0] = f2bf(f0.x); o[1] = f2bf(f0.y); o[2] = f2bf(f0.z); o[3] = f2bf(f0.w);
  o[4] = f2bf(f1.x); o[5] = f2bf(f1.y); o[6] = f2bf(f1.z); o[7] = f2bf(f1.w);
  *(u16x8*)(d + idx) = o;
}

// ======= bf16 MFMA GEMM (m97-style global_load_lds staging) ================
template <int MODE>
__device__ __forceinline__ void gemm_bf16(
    const unsigned short* __restrict__ X, const unsigned short* __restrict__ W,
    const float* __restrict__ bias, void* __restrict__ out, int row0, int col0,
    unsigned short* __restrict__ As, unsigned short* __restrict__ Bs) {
  const int tid = threadIdx.x;
  const int wid = tid >> 6, lane = tid & 63;
  const int lr = lane & 15, lk = (lane >> 4) << 3;
  const int qrow = (lane >> 4) << 2;
  const int wr = (wid & 1) << 6, wc = (wid >> 1) << 6;
  const int srow = (wid << 4) + (lane >> 2);
  const int scol = (lane & 3) << 3;
  const unsigned short* gA0 = X + (size_t)(row0 + srow) * C_ + scol;
  const unsigned short* gA1 = X + (size_t)(row0 + 64 + srow) * C_ + scol;
  const unsigned short* gB0 = W + (size_t)(col0 + srow) * C_ + scol;
  const unsigned short* gB1 = W + (size_t)(col0 + 64 + srow) * C_ + scol;
  unsigned short* lA0 = As + (wid << 9);
  unsigned short* lA1 = As + 2048 + (wid << 9);
  unsigned short* lB0 = Bs + (wid << 9);
  unsigned short* lB1 = Bs + 2048 + (wid << 9);
  f32x4 acc[4][4] = {};
  for (int k0 = 0; k0 < C_; k0 += 32) {
    gload16(gA0 + k0, lA0);
    gload16(gA1 + k0, lA1);
    gload16(gB0 + k0, lB0);
    gload16(gB1 + k0, lB1);
    __syncthreads();
    bf16x8 af[4], bg[4];
#pragma unroll
    for (int m = 0; m < 4; ++m)
      af[m] = *(const bf16x8*)&As[(wr + (m << 4) + lr) * 32 + lk];
#pragma unroll
    for (int n = 0; n < 4; ++n)
      bg[n] = *(const bf16x8*)&Bs[(wc + (n << 4) + lr) * 32 + lk];
#pragma unroll
    for (int m = 0; m < 4; ++m)
#pragma unroll
      for (int n = 0; n < 4; ++n)
        acc[m][n] = __builtin_amdgcn_mfma_f32_16x16x32_bf16(af[m], bg[n],
                                                            acc[m][n], 0, 0, 0);
    __syncthreads();
  }
#pragma unroll
  for (int m = 0; m < 4; ++m) {
#pragma unroll
    for (int n = 0; n < 4; ++n) {
      const int colc = col0 + wc + (n << 4) + lr;
      const float bv = bias[colc];
      if (MODE == 2) {
        const int r0 = row0 + wr + (m << 4) + qrow;
        const int bb = r0 >> 10, nn0 = r0 & 1023;
        const int hh = colc >> 6, dd = colc & 63;
        ushort4 pk;
        pk.x = f2bf(acc[m][n][0] + bv);
        pk.y = f2bf(acc[m][n][1] + bv);
        pk.z = f2bf(acc[m][n][2] + bv);
        pk.w = f2bf(acc[m][n][3] + bv);
        *(ushort4*)&((unsigned short*)out)[(((size_t)(bb * H_ + hh) << 6) + dd)
                                               * 1024 + nn0] = pk;
      } else {
#pragma unroll
        for (int q = 0; q < 4; ++q) {
          const int r = row0 + wr + (m << 4) + qrow + q;
          const float v = acc[m][n][q] + bv;
          if (MODE == 0) {
            ((float*)out)[(size_t)r * C_ + colc] = v;
          } else {
            const int bb = r >> 10, nn = r & 1023;
            const int hh = colc >> 6, dd = colc & 63;
            ((unsigned short*)out)[(((size_t)(bb * H_ + hh) << 10) + nn) * 64 +
                                   dd] = f2bf(v);
          }
        }
      }
    }
  }
}

__global__ __launch_bounds__(256) void proj3(
    const unsigned short* __restrict__ Xb, const unsigned short* __restrict__ Wb,
    const float* __restrict__ bq, const float* __restrict__ bk,
    const float* __restrict__ bv, unsigned short* Qb, unsigned short* Kb,
    unsigned short* Vt) {
  __shared__ __align__(16) unsigned short As[128 * 32];
  __shared__ __align__(16) unsigned short Bs[128 * 32];
  const int wg = blockIdx.x;
  const int nid = (wg & 7) * 144 + (wg >> 3);
  const int x = nid % 6, y = (nid / 6) & 63, z = nid / 384;
  const unsigned short* X = Xb + (size_t)z * B_ * N_ * C_;
  const unsigned short* W = Wb + (size_t)z * C_ * C_;
  if (z == 0)
    gemm_bf16<1>(X, W, bq, Qb, y << 7, x << 7, As, Bs);
  else if (z == 1)
    gemm_bf16<1>(X, W, bk, Kb, y << 7, x << 7, As, Bs);
  else
    gemm_bf16<2>(X, W, bv, Vt, y << 7, x << 7, As, Bs);
}

__global__ __launch_bounds__(256) void oproj(
    const unsigned short* __restrict__ X, const unsigned short* __restrict__ Wb,
    const float* __restrict__ bo, float* __restrict__ out) {
  __shared__ __align__(16) unsigned short As[128 * 32];
  __shared__ __align__(16) unsigned short Bs[128 * 32];
  const int wg = blockIdx.x;
  const int nid = (wg & 7) * 48 + (wg >> 3);
  const int x = nid % 6, y = nid / 6;
  gemm_bf16<0>(X, Wb + (size_t)3 * C_ * C_, bo, out, y << 7, x << 7, As, Bs);
}

// ============ fused: conv-folded QK^T (swapped) -> reg softmax -> PV =======
// QBLK=64 via q-register-blocking (R16 best-measured config, 177.5 us total).
// LDS blob (52,800 B):
//   [0)      K: [2 heads][66 rows] x 128 B, chunk^(row&7) swizzle
//   [16896)  V: [2 heads][64 d]    x 128 B, swizzled
//   [33280)  QPt: u16 [2][66][72] Q stage; later per-wave Pt [4][2][16][72]
//   [52288)  lsum: f32 [2][64]
__global__ __launch_bounds__(256, 2) void fused_attn(
    const unsigned short* __restrict__ Qb, const unsigned short* __restrict__ Kb,
    const unsigned short* __restrict__ Vt, const float* __restrict__ cw,
    const float* __restrict__ hm, unsigned short* __restrict__ pvout) {
  __shared__ __align__(16) unsigned char smem[52800];
  unsigned short* QPt = (unsigned short*)(smem + 33280);
  float* lsum = (float*)(smem + 52288);  // [h][row] = lsum[h*64+row]
#define KBASE(hh) (smem + (size_t)(hh)*8448)
#define VBASE(hh) (smem + 16896 + (size_t)(hh)*8192)

  const int wg = blockIdx.x;  // 768 = 8 * 96
  const int nid = (wg & 7) * 96 + (wg >> 3);
  const int qt = nid & 15;
  const int bg = nid >> 4;
  const int g = bg % G_, bb = bg / G_;
  const int i0 = qt << 6;

  const int tid = threadIdx.x;
  const int wid = tid >> 6, lane = tid & 63;
  const int lr = lane & 15, lg = lane >> 4;
  const int lk = lg << 3;

  const int h = wid >> 1, mt = wid & 1;  // wave role: (head, 32-row q-half)

  const size_t HSTR = (size_t)N_ * 64;
  const unsigned short* Qz = Qb + (size_t)(bb * H_ + 2 * g) * HSTR;
  const unsigned short* Kz = Kb + (size_t)(bb * H_ + 2 * g) * HSTR;
  const unsigned short* Vz = Vt + (size_t)(bb * H_ + 2 * g) * HSTR;  // [h][d][n]

  // staging roles (depend on KSTEP only)
  const int krow = tid >> 2, kd0 = (tid & 3) << 4;        // K rows 0..63
  const int kc0 = (tid & 3) << 1;                         // 16B chunks 0,2,4,6
  const int k2r = 64 + (tid >> 3), k2d = (tid & 7) << 3;  // halo rows (tid<16)
  const int vd = tid >> 2, vc0 = (tid & 3) << 4;          // V^T rows

  u16x8 kreg[4], vreg[4];
  u16x8 kreg2[2];

  // ---- prefetch step 0 ----
  {
    const int gj = -1 + krow;
#pragma unroll
    for (int hh = 0; hh < 2; ++hh) {
      u16x8 a = {}, b = {};
      if (gj >= 0) {
        a = *(const u16x8*)(Kz + hh * HSTR + (size_t)gj * 64 + kd0);
        b = *(const u16x8*)(Kz + hh * HSTR + (size_t)gj * 64 + kd0 + 8);
      }
      kreg[2 * hh] = a; kreg[2 * hh + 1] = b;
    }
    if (tid < 16) {
      const int gj2 = -1 + k2r;  // 63 or 64
#pragma unroll
      for (int hh = 0; hh < 2; ++hh)
        kreg2[hh] = *(const u16x8*)(Kz + hh * HSTR + (size_t)gj2 * 64 + k2d);
    }
#pragma unroll
    for (int hh = 0; hh < 2; ++hh)
#pragma unroll
      for (int hf = 0; hf < 2; ++hf)
        vreg[2 * hh + hf] =
            *(const u16x8*)(Vz + hh * HSTR + (size_t)vd * 1024 + vc0 + (hf << 3));
  }

  // ---- stage Q rows i0-1 .. i0+64 (66 rows, OOB -> 0) into QPt ----
  {
    const int r = tid >> 2, d0 = (tid & 3) << 4;  // 64 rows, 32B per thread
    const int gi = i0 - 1 + r;
#pragma unroll
    for (int hh = 0; hh < 2; ++hh) {
      u16x8 qa = {}, qb = {};
      if (gi >= 0 && gi < N_) {
        qa = *(const u16x8*)(Qz + hh * HSTR + (size_t)gi * 64 + d0);
        qb = *(const u16x8*)(Qz + hh * HSTR + (size_t)gi * 64 + d0 + 8);
      }
      *(u16x8*)&QPt[((size_t)(hh * 66 + r)) * 72 + d0] = qa;
      *(u16x8*)&QPt[((size_t)(hh * 66 + r)) * 72 + d0 + 8] = qb;
    }
    if (tid < 16) {
      const int r2 = 64 + (tid >> 3);         // rows 64,65
      const int d0h = (tid & 7) << 3;
      const int gi2 = i0 - 1 + r2;            // i0+63, i0+64
#pragma unroll
      for (int hh = 0; hh < 2; ++hh) {
        u16x8 qv = {};
        if (gi2 < N_)
          qv = *(const u16x8*)(Qz + hh * HSTR + (size_t)gi2 * 64 + d0h);
        *(u16x8*)&QPt[((size_t)(hh * 66 + r2)) * 72 + d0h] = qv;
      }
    }
  }
  __syncthreads();  // Q staged

  // ---- extract Qtilde fragments for both q-subtiles ----
  // weights folded: *0.125 (1/sqrt(D)) and *log2(e) (exp2 domain)
  bf16x8 qtf[2][3][2];  // [qs][c][dh]
  {
    float wc3[3][3];
#pragma unroll
    for (int a = 0; a < 3; ++a)
#pragma unroll
      for (int c = 0; c < 3; ++c)
        wc3[a][c] = cw[(2 * g + h) * 9 + a * 3 + c] *
                    (0.125f * 1.4426950408889634f);
#pragma unroll
    for (int qs = 0; qs < 2; ++qs) {
      const int ribase = (mt << 5) + (qs << 4) + lr;
#pragma unroll
      for (int dh = 0; dh < 2; ++dh) {
        const u16x8 qa =
            *(const u16x8*)&QPt[((size_t)(h * 66 + ribase + 0)) * 72 +
                                (dh << 5) + lk];
        const u16x8 qb =
            *(const u16x8*)&QPt[((size_t)(h * 66 + ribase + 1)) * 72 +
                                (dh << 5) + lk];
        const u16x8 qc =
            *(const u16x8*)&QPt[((size_t)(h * 66 + ribase + 2)) * 72 +
                                (dh << 5) + lk];
#pragma unroll
        for (int c = 0; c < 3; ++c) {
#pragma unroll
          for (int e = 0; e < 8; ++e) {
            const float v = bf2f(qa[e]) * wc3[0][c] + bf2f(qb[e]) * wc3[1][c] +
                            bf2f(qc[e]) * wc3[2][c];
            qtf[qs][c][dh][e] = (short)f2bf(v);
          }
        }
      }
    }
  }
  // (B1 of step 0 fences all waves' Q reads before first Pt overwrite.)

  unsigned short* PtW = &QPt[(size_t)wid * 2304];  // per-wave [2][16][72]

  // precomputed swizzled read offsets (row&7 = (lr+c)&7 for K, lr&7 for V)
  const unsigned char* kbB = KBASE(h) + lr * 128;
  int kofs[3][2];
#pragma unroll
  for (int c = 0; c < 3; ++c)
#pragma unroll
    for (int dh = 0; dh < 2; ++dh)
      kofs[c][dh] = (((((dh << 2) + lg) ^ ((lr + c) & 7)) << 4)) + c * 128;
  const unsigned char* vbB0 = VBASE(0) + lr * 128;
  const unsigned char* vbB1 = VBASE(1) + lr * 128;
  int vofs[2];
#pragma unroll
  for (int kj = 0; kj < 2; ++kj)
    vofs[kj] = ((((kj << 2) + lg) ^ (lr & 7)) << 4);

  float mreg[2] = {-3.0e38f, -3.0e38f};
  float lreg[2] = {0.f, 0.f};
  f32x4 acc[2][2][4] = {};  // [v-head k2][qs][nt(d)]

  for (int s = 0; s < NKS; ++s) {
    // ---- phase 1: write staged K/V regs to LDS (swizzled chunks) ----
    {
      unsigned char* kr0 = KBASE(0) + krow * 128;
      unsigned char* kr1 = KBASE(1) + krow * 128;
      const int ksw = krow & 7;
      *(u16x8*)(kr0 + ((kc0 ^ ksw) << 4)) = kreg[0];
      *(u16x8*)(kr0 + (((kc0 + 1) ^ ksw) << 4)) = kreg[1];
      *(u16x8*)(kr1 + ((kc0 ^ ksw) << 4)) = kreg[2];
      *(u16x8*)(kr1 + (((kc0 + 1) ^ ksw) << 4)) = kreg[3];
      if (tid < 16) {
        const int k2sw = k2r & 7, k2c = tid & 7;
        *(u16x8*)(KBASE(0) + k2r * 128 + ((k2c ^ k2sw) << 4)) = kreg2[0];
        *(u16x8*)(KBASE(1) + k2r * 128 + ((k2c ^ k2sw) << 4)) = kreg2[1];
      }
      unsigned char* vr0 = VBASE(0) + vd * 128;
      unsigned char* vr1 = VBASE(1) + vd * 128;
      const int vsw = vd & 7, vcc = (tid & 3) << 1;
      *(u16x8*)(vr0 + ((vcc ^ vsw) << 4)) = vreg[0];
      *(u16x8*)(vr0 + (((vcc + 1) ^ vsw) << 4)) = vreg[1];
      *(u16x8*)(vr1 + ((vcc ^ vsw) << 4)) = vreg[2];
      *(u16x8*)(vr1 + (((vcc + 1) ^ vsw) << 4)) = vreg[3];
    }
    __syncthreads();  // B1

    // ---- phase 2: issue loads for step s+1 ----
    if (s + 1 < NKS) {
      const int j1 = (s + 1) << 6;
      const int gj = j1 - 1 + krow;
#pragma unroll
      for (int hh = 0; hh < 2; ++hh) {
        kreg[2 * hh] = *(const u16x8*)(Kz + hh * HSTR + (size_t)gj * 64 + kd0);
        kreg[2 * hh + 1] =
            *(const u16x8*)(Kz + hh * HSTR + (size_t)gj * 64 + kd0 + 8);
      }
      if (tid < 16) {
        const int gj2 = j1 - 1 + k2r;
#pragma unroll
        for (int hh = 0; hh < 2; ++hh) {
          u16x8 a = {};
          if (gj2 < N_)
            a = *(const u16x8*)(Kz + hh * HSTR + (size_t)gj2 * 64 + k2d);
          kreg2[hh] = a;
        }
      }
#pragma unroll
      for (int hh = 0; hh < 2; ++hh)
#pragma unroll
        for (int hf = 0; hf < 2; ++hf)
          vreg[2 * hh + hf] = *(const u16x8*)(Vz + hh * HSTR + (size_t)vd * 1024 +
                                              j1 + vc0 + (hf << 3));
    }

    // ---- phase 3: swapped conv-QK^T, K-frag shared across both qs ----
    f32x4 racc[2][4] = {};
    __builtin_amdgcn_s_setprio(1);
#pragma unroll
    for (int c = 0; c < 3; ++c) {
#pragma unroll
      for (int dh = 0; dh < 2; ++dh) {
#pragma unroll
        for (int nt = 0; nt < 4; ++nt) {
          const bf16x8 ak = *(const bf16x8*)(kbB + nt * 2048 + kofs[c][dh]);
          racc[0][nt] = __builtin_amdgcn_mfma_f32_16x16x32_bf16(
              ak, qtf[0][c][dh], racc[0][nt], 0, 0, 0);
          racc[1][nt] = __builtin_amdgcn_mfma_f32_16x16x32_bf16(
              ak, qtf[1][c][dh], racc[1][nt], 0, 0, 0);
        }
      }
    }
    __builtin_amdgcn_s_setprio(0);

    // ---- phase 4: per-lane online softmax (log2 domain, defer-max) ----
    {
      float pmax[2];
#pragma unroll
      for (int qs = 0; qs < 2; ++qs) {
        float pm = fmaxf(fmaxf(racc[qs][0][0], racc[qs][0][1]),
                         fmaxf(racc[qs][0][2], racc[qs][0][3]));
#pragma unroll
        for (int nt = 1; nt < 4; ++nt)
          pm = fmaxf(pm, fmaxf(fmaxf(racc[qs][nt][0], racc[qs][nt][1]),
                               fmaxf(racc[qs][nt][2], racc[qs][nt][3])));
        pm = fmaxf(pm, __shfl_xor(pm, 16));
        pm = fmaxf(pm, __shfl_xor(pm, 32));
        pmax[qs] = pm;
      }
      if (__any((pmax[0] > mreg[0] + 8.f) || (pmax[1] > mreg[1] + 8.f))) {
#pragma unroll
        for (int qs = 0; qs < 2; ++qs) {
          const float mn = fmaxf(mreg[qs], pmax[qs]);
          const float alpha = exp2f(mreg[qs] - mn);
          mreg[qs] = mn;
          lreg[qs] *= alpha;
          float a4[4];
#pragma unroll
          for (int q = 0; q < 4; ++q)
            a4[q] = __shfl(alpha, (lg << 4) | ((lg << 2) + q));
#pragma unroll
          for (int k2 = 0; k2 < 2; ++k2)
#pragma unroll
            for (int nt = 0; nt < 4; ++nt)
#pragma unroll
              for (int q = 0; q < 4; ++q) acc[k2][qs][nt][q] *= a4[q];
        }
      }
#pragma unroll
      for (int qs = 0; qs < 2; ++qs) {
        float rs = 0.f;
#pragma unroll
        for (int nt = 0; nt < 4; ++nt)
#pragma unroll
          for (int q = 0; q < 4; ++q) {
            const float p = exp2f(racc[qs][nt][q] - mreg[qs]);
            racc[qs][nt][q] = p;
            rs += p;
          }
        rs += __shfl_xor(rs, 16);
        rs += __shfl_xor(rs, 32);
        lreg[qs] += rs;
#pragma unroll
        for (int nt = 0; nt < 4; ++nt) {
          ushort4 pw;
          pw.x = f2bf(racc[qs][nt][0]); pw.y = f2bf(racc[qs][nt][1]);
          pw.z = f2bf(racc[qs][nt][2]); pw.w = f2bf(racc[qs][nt][3]);
          *(ushort4*)&PtW[(size_t)qs * 1152 + (size_t)lr * 72 + (nt << 4) +
                          (lg << 2)] = pw;
        }
      }
    }

    // ---- phase 5: PV (both v-heads), V-frag shared across both qs ----
    {
      bf16x8 paf[2][2];
#pragma unroll
      for (int qs = 0; qs < 2; ++qs) {
        paf[qs][0] = *(const bf16x8*)&PtW[(size_t)qs * 1152 + (size_t)lr * 72 + lk];
        paf[qs][1] =
            *(const bf16x8*)&PtW[(size_t)qs * 1152 + (size_t)lr * 72 + 32 + lk];
      }
      __builtin_amdgcn_s_setprio(1);
#pragma unroll
      for (int kj = 0; kj < 2; ++kj)
#pragma unroll
        for (int nt = 0; nt < 4; ++nt) {
          const bf16x8 bva = *(const bf16x8*)(vbB0 + nt * 2048 + vofs[kj]);
          const bf16x8 bvb = *(const bf16x8*)(vbB1 + nt * 2048 + vofs[kj]);
#pragma unroll
          for (int qs = 0; qs < 2; ++qs) {
            acc[0][qs][nt] = __builtin_amdgcn_mfma_f32_16x16x32_bf16(
                paf[qs][kj], bva, acc[0][qs][nt], 0, 0, 0);
            acc[1][qs][nt] = __builtin_amdgcn_mfma_f32_16x16x32_bf16(
                paf[qs][kj], bvb, acc[1][qs][nt], 0, 0, 0);
          }
        }
      __builtin_amdgcn_s_setprio(0);
    }
    __syncthreads();  // B3 (protects K/V LDS for next staging)
  }

  // ---- epilogue: O_k = sum_h hm[h,k]/l_h * A_hk ----
  if (lg == 0) {
    lsum[h * 64 + (mt << 5) + lr] = lreg[0];
    lsum[h * 64 + (mt << 5) + 16 + lr] = lreg[1];
  }
  __syncthreads();

  const float mw0 = hm[(g * 2 + h) * 2 + 0];
  const float mw1 = hm[(g * 2 + h) * 2 + 1];
  float* Os = (float*)smem;  // [2k2][64 rows][68] f32 = 34,816 B (< lsum ofs)
  if (h == 1) {
#pragma unroll
    for (int qs = 0; qs < 2; ++qs)
#pragma unroll
      for (int q = 0; q < 4; ++q) {
        const int row = (mt << 5) + (qs << 4) + (lg << 2) + q;
        const float f0 = mw0 / lsum[64 + row];
        const float f1 = mw1 / lsum[64 + row];
#pragma unroll
        for (int nt = 0; nt < 4; ++nt) {
          Os[(size_t)(0 * 64 + row) * 68 + (nt << 4) + lr] =
              acc[0][qs][nt][q] * f0;
          Os[(size_t)(1 * 64 + row) * 68 + (nt << 4) + lr] =
              acc[1][qs][nt][q] * f1;
        }
      }
  }
  __syncthreads();
  if (h == 0) {
#pragma unroll
    for (int qs = 0; qs < 2; ++qs)
#pragma unroll
      for (int q = 0; q < 4; ++q) {
        const int row = (mt << 5) + (qs << 4) + (lg << 2) + q;
        const int gi = i0 + row;
        const float f0 = mw0 / lsum[row];
        const float f1 = mw1 / lsum[row];
#pragma unroll
        for (int nt = 0; nt < 4; ++nt) {
          const float v0 = acc[0][qs][nt][q] * f0 +
                           Os[(size_t)(0 * 64 + row) * 68 + (nt << 4) + lr];
          const float v1 = acc[1][qs][nt][q] * f1 +
                           Os[(size_t)(1 * 64 + row) * 68 + (nt << 4) + lr];
          pvout[(size_t)(bb * N_ + gi) * C_ + (2 * g + 0) * 64 + (nt << 4) +
                lr] = f2bf(v0);
          pvout[(size_t)(bb * N_ + gi) * C_ + (2 * g + 1) * 64 + (nt << 4) +
                lr] = f2bf(v1);
        }
      }
  }
#undef KBASE
#undef VBASE
}

extern "C" void kernel_launch(void* const* d_in, const int* in_sizes, int n_in,
                              void* d_out, int out_size, void* d_ws, size_t ws_size,
                              hipStream_t stream) {
  const float* query = (const float*)d_in[0];
  const float* key   = (const float*)d_in[1];
  const float* value = (const float*)d_in[2];
  const float* Wq = (const float*)d_in[3];
  const float* bq = (const float*)d_in[4];
  const float* Wk = (const float*)d_in[5];
  const float* bk = (const float*)d_in[6];
  const float* Wv = (const float*)d_in[7];
  const float* bv = (const float*)d_in[8];
  const float* cw = (const float*)d_in[9];
  const float* hm = (const float*)d_in[10];
  const float* Wo = (const float*)d_in[11];
  const float* bo = (const float*)d_in[12];
  float* out = (float*)d_out;

  char* ws = (char*)d_ws;
  const size_t SZ_BF = (size_t)B_ * H_ * N_ * 64 * 2;  // 12,582,912 B
  unsigned short* Qb = (unsigned short*)ws;
  unsigned short* Kb = (unsigned short*)(ws + SZ_BF);
  unsigned short* Vt = (unsigned short*)(ws + 2 * SZ_BF);   // (B,H,D,N)
  unsigned short* pvb = (unsigned short*)(ws + 3 * SZ_BF);  // bf16 (B,N,C)
  unsigned short* Xb = (unsigned short*)(ws + 4 * SZ_BF);   // q,k,v bf16
  unsigned short* Wb = (unsigned short*)(ws + 7 * SZ_BF);   // Wq,Wk,Wv,Wo bf16

  const dim3 blk(256);
  cvtX<<<dim3(3072, 3), blk, 0, stream>>>(query, key, value, Xb);
  cvtW<<<dim3(288, 4), blk, 0, stream>>>(Wq, Wk, Wv, Wo, Wb);
  proj3<<<dim3(1152), blk, 0, stream>>>(Xb, Wb, bq, bk, bv, Qb, Kb, Vt);
  fused_attn<<<dim3(768), blk, 0, stream>>>(Qb, Kb, Vt, cw, hm, pvb);
  oproj<<<dim3(384), blk, 0, stream>>>(pvb, Wb, bo, out);
}

// Round 19
// 172.599 us; speedup vs baseline: 1.1797x; 1.0290x over previous
//
#include <hip/hip_runtime.h>
#include <stdint.h>

#define B_ 8
#define N_ 1024
#define C_ 768
#define H_ 12
#define G_ 6
#define QBLK 64
#define KSTEP 64
#define NQT 16   // 1024/64
#define NKS 16   // 1024/64

typedef __attribute__((ext_vector_type(8))) short bf16x8;
typedef __attribute__((ext_vector_type(8))) unsigned short u16x8;
typedef __attribute__((ext_vector_type(4))) float f32x4;

__device__ __forceinline__ float bf2f(unsigned short u) {
  return __uint_as_float(((unsigned)u) << 16);
}
// float -> bf16 (RNE) via hardware cast (compiler emits v_cvt_pk_bf16_f32).
__device__ __forceinline__ unsigned short f2bf(float f) {
  __bf16 b = (__bf16)f;
  unsigned short u;
  __builtin_memcpy(&u, &b, 2);
  return u;
}
__device__ __forceinline__ void gload16(const void* g, void* l) {
  __builtin_amdgcn_global_load_lds(
      (const __attribute__((address_space(1))) unsigned int*)g,
      (__attribute__((address_space(3))) unsigned int*)l, 16, 0, 0);
}

// ---------------- fp32 -> bf16 conversion (weights only) -------------------
__global__ __launch_bounds__(256) void cvtW(
    const float* __restrict__ wq, const float* __restrict__ wk,
    const float* __restrict__ wv, const float* __restrict__ wo,
    unsigned short* __restrict__ dst) {
  const float* src = (blockIdx.y == 0)   ? wq
                     : (blockIdx.y == 1) ? wk
                     : (blockIdx.y == 2) ? wv
                                         : wo;
  unsigned short* d = dst + (size_t)blockIdx.y * ((size_t)C_ * C_);
  const size_t idx = ((size_t)blockIdx.x * 256 + threadIdx.x) * 8;
  const float4 f0 = *(const float4*)(src + idx);
  const float4 f1 = *(const float4*)(src + idx + 4);
  u16x8 o;
  o[0] = f2bf(f0.x); o[1] = f2bf(f0.y); o[2] = f2bf(f0.z); o[3] = f2bf(f0.w);
  o[4] = f2bf(f1.x); o[5] = f2bf(f1.y); o[6] = f2bf(f1.z); o[7] = f2bf(f1.w);
  *(u16x8*)(d + idx) = o;
}

// ======= GEMM variant A: X fp32 (reg-staged + in-loop cvt), W bf16 =========
// 128x128 tile, BK=32, 4 waves. As [128][40] u16 (padded), Bs [128][32] u16.
// MODE 1: bf16 (B,H,N,D). MODE 2: bf16 (B,H,D,N).
template <int MODE>
__device__ __forceinline__ void gemm_af32(
    const float* __restrict__ X, const unsigned short* __restrict__ W,
    const float* __restrict__ bias, void* __restrict__ out, int row0, int col0,
    unsigned short* __restrict__ As, unsigned short* __restrict__ Bs) {
  const int tid = threadIdx.x;
  const int wid = tid >> 6, lane = tid & 63;
  const int lr = lane & 15, lk = (lane >> 4) << 3;
  const int qrow = (lane >> 4) << 2;
  const int wr = (wid & 1) << 6, wc = (wid >> 1) << 6;
  // A staging: row = tid>>1 (0..127), half = tid&1 covers 16 floats (64 B)
  const int arow = tid >> 1, ahalf = tid & 1;
  const float* gA = X + (size_t)(row0 + arow) * C_ + (ahalf << 4);
  // B staging via global_load_lds (unchanged, linear [128][32])
  const int srow = (wid << 4) + (lane >> 2);
  const int scol = (lane & 3) << 3;
  const unsigned short* gB0 = W + (size_t)(col0 + srow) * C_ + scol;
  const unsigned short* gB1 = W + (size_t)(col0 + 64 + srow) * C_ + scol;
  unsigned short* lB0 = Bs + (wid << 9);
  unsigned short* lB1 = Bs + 2048 + (wid << 9);
  f32x4 pa0 = *(const f32x4*)(gA);
  f32x4 pa1 = *(const f32x4*)(gA + 4);
  f32x4 pa2 = *(const f32x4*)(gA + 8);
  f32x4 pa3 = *(const f32x4*)(gA + 12);
  f32x4 acc[4][4] = {};
  for (int k0 = 0; k0 < C_; k0 += 32) {
    // convert staged A regs -> bf16 LDS (padded pitch 40)
    {
      u16x8 w0, w1;
#pragma unroll
      for (int e = 0; e < 4; ++e) { w0[e] = f2bf(pa0[e]); w0[4 + e] = f2bf(pa1[e]); }
#pragma unroll
      for (int e = 0; e < 4; ++e) { w1[e] = f2bf(pa2[e]); w1[4 + e] = f2bf(pa3[e]); }
      unsigned short* dstA = &As[arow * 40 + (ahalf << 4)];
      *(u16x8*)dstA = w0;
      *(u16x8*)(dstA + 8) = w1;
    }
    gload16(gB0 + k0, lB0);
    gload16(gB1 + k0, lB1);
    __syncthreads();  // drains B gload + A ds_writes
    if (k0 + 32 < C_) {
      pa0 = *(const f32x4*)(gA + k0 + 32);
      pa1 = *(const f32x4*)(gA + k0 + 36);
      pa2 = *(const f32x4*)(gA + k0 + 40);
      pa3 = *(const f32x4*)(gA + k0 + 44);
    }
    bf16x8 af[4], bg[4];
#pragma unroll
    for (int m = 0; m < 4; ++m)
      af[m] = *(const bf16x8*)&As[(wr + (m << 4) + lr) * 40 + lk];
#pragma unroll
    for (int n = 0; n < 4; ++n)
      bg[n] = *(const bf16x8*)&Bs[(wc + (n << 4) + lr) * 32 + lk];
#pragma unroll
    for (int m = 0; m < 4; ++m)
#pragma unroll
      for (int n = 0; n < 4; ++n)
        acc[m][n] = __builtin_amdgcn_mfma_f32_16x16x32_bf16(af[m], bg[n],
                                                            acc[m][n], 0, 0, 0);
    __syncthreads();
  }
#pragma unroll
  for (int m = 0; m < 4; ++m) {
#pragma unroll
    for (int n = 0; n < 4; ++n) {
      const int colc = col0 + wc + (n << 4) + lr;
      const float bv = bias[colc];
      if (MODE == 2) {
        const int r0 = row0 + wr + (m << 4) + qrow;
        const int bb = r0 >> 10, nn0 = r0 & 1023;
        const int hh = colc >> 6, dd = colc & 63;
        ushort4 pk;
        pk.x = f2bf(acc[m][n][0] + bv);
        pk.y = f2bf(acc[m][n][1] + bv);
        pk.z = f2bf(acc[m][n][2] + bv);
        pk.w = f2bf(acc[m][n][3] + bv);
        *(ushort4*)&((unsigned short*)out)[(((size_t)(bb * H_ + hh) << 6) + dd)
                                               * 1024 + nn0] = pk;
      } else {
#pragma unroll
        for (int q = 0; q < 4; ++q) {
          const int r = row0 + wr + (m << 4) + qrow + q;
          const int bb = r >> 10, nn = r & 1023;
          const int hh = colc >> 6, dd = colc & 63;
          ((unsigned short*)out)[(((size_t)(bb * H_ + hh) << 10) + nn) * 64 +
                                 dd] = f2bf(acc[m][n][q] + bv);
        }
      }
    }
  }
}

// ======= GEMM variant B: both bf16 (m97-style gload_lds) — for oproj =======
__device__ __forceinline__ void gemm_bf16_o(
    const unsigned short* __restrict__ X, const unsigned short* __restrict__ W,
    const float* __restrict__ bias, float* __restrict__ out, int row0, int col0,
    unsigned short* __restrict__ As, unsigned short* __restrict__ Bs) {
  const int tid = threadIdx.x;
  const int wid = tid >> 6, lane = tid & 63;
  const int lr = lane & 15, lk = (lane >> 4) << 3;
  const int qrow = (lane >> 4) << 2;
  const int wr = (wid & 1) << 6, wc = (wid >> 1) << 6;
  const int srow = (wid << 4) + (lane >> 2);
  const int scol = (lane & 3) << 3;
  const unsigned short* gA0 = X + (size_t)(row0 + srow) * C_ + scol;
  const unsigned short* gA1 = X + (size_t)(row0 + 64 + srow) * C_ + scol;
  const unsigned short* gB0 = W + (size_t)(col0 + srow) * C_ + scol;
  const unsigned short* gB1 = W + (size_t)(col0 + 64 + srow) * C_ + scol;
  unsigned short* lA0 = As + (wid << 9);
  unsigned short* lA1 = As + 2048 + (wid << 9);
  unsigned short* lB0 = Bs + (wid << 9);
  unsigned short* lB1 = Bs + 2048 + (wid << 9);
  f32x4 acc[4][4] = {};
  for (int k0 = 0; k0 < C_; k0 += 32) {
    gload16(gA0 + k0, lA0);
    gload16(gA1 + k0, lA1);
    gload16(gB0 + k0, lB0);
    gload16(gB1 + k0, lB1);
    __syncthreads();
    bf16x8 af[4], bg[4];
#pragma unroll
    for (int m = 0; m < 4; ++m)
      af[m] = *(const bf16x8*)&As[(wr + (m << 4) + lr) * 32 + lk];
#pragma unroll
    for (int n = 0; n < 4; ++n)
      bg[n] = *(const bf16x8*)&Bs[(wc + (n << 4) + lr) * 32 + lk];
#pragma unroll
    for (int m = 0; m < 4; ++m)
#pragma unroll
      for (int n = 0; n < 4; ++n)
        acc[m][n] = __builtin_amdgcn_mfma_f32_16x16x32_bf16(af[m], bg[n],
                                                            acc[m][n], 0, 0, 0);
    __syncthreads();
  }
#pragma unroll
  for (int m = 0; m < 4; ++m) {
#pragma unroll
    for (int n = 0; n < 4; ++n) {
      const int colc = col0 + wc + (n << 4) + lr;
      const float bv = bias[colc];
#pragma unroll
      for (int q = 0; q < 4; ++q) {
        const int r = row0 + wr + (m << 4) + qrow + q;
        out[(size_t)r * C_ + colc] = acc[m][n][q] + bv;
      }
    }
  }
}

__global__ __launch_bounds__(256) void proj3(
    const float* __restrict__ q, const float* __restrict__ k,
    const float* __restrict__ v, const unsigned short* __restrict__ Wb,
    const float* __restrict__ bq, const float* __restrict__ bk,
    const float* __restrict__ bv, unsigned short* Qb, unsigned short* Kb,
    unsigned short* Vt) {
  __shared__ __align__(16) unsigned short As[128 * 40];
  __shared__ __align__(16) unsigned short Bs[128 * 32];
  const int wg = blockIdx.x;
  const int nid = (wg & 7) * 144 + (wg >> 3);
  const int x = nid % 6, y = (nid / 6) & 63, z = nid / 384;
  const unsigned short* W = Wb + (size_t)z * C_ * C_;
  if (z == 0)
    gemm_af32<1>(q, W, bq, Qb, y << 7, x << 7, As, Bs);
  else if (z == 1)
    gemm_af32<1>(k, W, bk, Kb, y << 7, x << 7, As, Bs);
  else
    gemm_af32<2>(v, W, bv, Vt, y << 7, x << 7, As, Bs);
}

__global__ __launch_bounds__(256) void oproj(
    const unsigned short* __restrict__ X, const unsigned short* __restrict__ Wb,
    const float* __restrict__ bo, float* __restrict__ out) {
  __shared__ __align__(16) unsigned short As[128 * 32];
  __shared__ __align__(16) unsigned short Bs[128 * 32];
  const int wg = blockIdx.x;
  const int nid = (wg & 7) * 48 + (wg >> 3);
  const int x = nid % 6, y = nid / 6;
  gemm_bf16_o(X, Wb + (size_t)3 * C_ * C_, bo, out, y << 7, x << 7, As, Bs);
}

// ============ fused: conv-folded QK^T (swapped) -> reg softmax -> PV =======
// QBLK=64 via q-register-blocking (R16 best-measured config, unchanged).
__global__ __launch_bounds__(256, 2) void fused_attn(
    const unsigned short* __restrict__ Qb, const unsigned short* __restrict__ Kb,
    const unsigned short* __restrict__ Vt, const float* __restrict__ cw,
    const float* __restrict__ hm, unsigned short* __restrict__ pvout) {
  __shared__ __align__(16) unsigned char smem[52800];
  unsigned short* QPt = (unsigned short*)(smem + 33280);
  float* lsum = (float*)(smem + 52288);  // [h][row] = lsum[h*64+row]
#define KBASE(hh) (smem + (size_t)(hh)*8448)
#define VBASE(hh) (smem + 16896 + (size_t)(hh)*8192)

  const int wg = blockIdx.x;  // 768 = 8 * 96
  const int nid = (wg & 7) * 96 + (wg >> 3);
  const int qt = nid & 15;
  const int bg = nid >> 4;
  const int g = bg % G_, bb = bg / G_;
  const int i0 = qt << 6;

  const int tid = threadIdx.x;
  const int wid = tid >> 6, lane = tid & 63;
  const int lr = lane & 15, lg = lane >> 4;
  const int lk = lg << 3;

  const int h = wid >> 1, mt = wid & 1;  // wave role: (head, 32-row q-half)

  const size_t HSTR = (size_t)N_ * 64;
  const unsigned short* Qz = Qb + (size_t)(bb * H_ + 2 * g) * HSTR;
  const unsigned short* Kz = Kb + (size_t)(bb * H_ + 2 * g) * HSTR;
  const unsigned short* Vz = Vt + (size_t)(bb * H_ + 2 * g) * HSTR;  // [h][d][n]

  // staging roles (depend on KSTEP only)
  const int krow = tid >> 2, kd0 = (tid & 3) << 4;        // K rows 0..63
  const int kc0 = (tid & 3) << 1;                         // 16B chunks 0,2,4,6
  const int k2r = 64 + (tid >> 3), k2d = (tid & 7) << 3;  // halo rows (tid<16)
  const int vd = tid >> 2, vc0 = (tid & 3) << 4;          // V^T rows

  u16x8 kreg[4], vreg[4];
  u16x8 kreg2[2];

  // ---- prefetch step 0 ----
  {
    const int gj = -1 + krow;
#pragma unroll
    for (int hh = 0; hh < 2; ++hh) {
      u16x8 a = {}, b = {};
      if (gj >= 0) {
        a = *(const u16x8*)(Kz + hh * HSTR + (size_t)gj * 64 + kd0);
        b = *(const u16x8*)(Kz + hh * HSTR + (size_t)gj * 64 + kd0 + 8);
      }
      kreg[2 * hh] = a; kreg[2 * hh + 1] = b;
    }
    if (tid < 16) {
      const int gj2 = -1 + k2r;  // 63 or 64
#pragma unroll
      for (int hh = 0; hh < 2; ++hh)
        kreg2[hh] = *(const u16x8*)(Kz + hh * HSTR + (size_t)gj2 * 64 + k2d);
    }
#pragma unroll
    for (int hh = 0; hh < 2; ++hh)
#pragma unroll
      for (int hf = 0; hf < 2; ++hf)
        vreg[2 * hh + hf] =
            *(const u16x8*)(Vz + hh * HSTR + (size_t)vd * 1024 + vc0 + (hf << 3));
  }

  // ---- stage Q rows i0-1 .. i0+64 (66 rows, OOB -> 0) into QPt ----
  {
    const int r = tid >> 2, d0 = (tid & 3) << 4;  // 64 rows, 32B per thread
    const int gi = i0 - 1 + r;
#pragma unroll
    for (int hh = 0; hh < 2; ++hh) {
      u16x8 qa = {}, qb = {};
      if (gi >= 0 && gi < N_) {
        qa = *(const u16x8*)(Qz + hh * HSTR + (size_t)gi * 64 + d0);
        qb = *(const u16x8*)(Qz + hh * HSTR + (size_t)gi * 64 + d0 + 8);
      }
      *(u16x8*)&QPt[((size_t)(hh * 66 + r)) * 72 + d0] = qa;
      *(u16x8*)&QPt[((size_t)(hh * 66 + r)) * 72 + d0 + 8] = qb;
    }
    if (tid < 16) {
      const int r2 = 64 + (tid >> 3);         // rows 64,65
      const int d0h = (tid & 7) << 3;
      const int gi2 = i0 - 1 + r2;            // i0+63, i0+64
#pragma unroll
      for (int hh = 0; hh < 2; ++hh) {
        u16x8 qv = {};
        if (gi2 < N_)
          qv = *(const u16x8*)(Qz + hh * HSTR + (size_t)gi2 * 64 + d0h);
        *(u16x8*)&QPt[((size_t)(hh * 66 + r2)) * 72 + d0h] = qv;
      }
    }
  }
  __syncthreads();  // Q staged

  // ---- extract Qtilde fragments for both q-subtiles ----
  // weights folded: *0.125 (1/sqrt(D)) and *log2(e) (exp2 domain)
  bf16x8 qtf[2][3][2];  // [qs][c][dh]
  {
    float wc3[3][3];
#pragma unroll
    for (int a = 0; a < 3; ++a)
#pragma unroll
      for (int c = 0; c < 3; ++c)
        wc3[a][c] = cw[(2 * g + h) * 9 + a * 3 + c] *
                    (0.125f * 1.4426950408889634f);
#pragma unroll
    for (int qs = 0; qs < 2; ++qs) {
      const int ribase = (mt << 5) + (qs << 4) + lr;
#pragma unroll
      for (int dh = 0; dh < 2; ++dh) {
        const u16x8 qa =
            *(const u16x8*)&QPt[((size_t)(h * 66 + ribase + 0)) * 72 +
                                (dh << 5) + lk];
        const u16x8 qb =
            *(const u16x8*)&QPt[((size_t)(h * 66 + ribase + 1)) * 72 +
                                (dh << 5) + lk];
        const u16x8 qc =
            *(const u16x8*)&QPt[((size_t)(h * 66 + ribase + 2)) * 72 +
                                (dh << 5) + lk];
#pragma unroll
        for (int c = 0; c < 3; ++c) {
#pragma unroll
          for (int e = 0; e < 8; ++e) {
            const float v = bf2f(qa[e]) * wc3[0][c] + bf2f(qb[e]) * wc3[1][c] +
                            bf2f(qc[e]) * wc3[2][c];
            qtf[qs][c][dh][e] = (short)f2bf(v);
          }
        }
      }
    }
  }
  // (B1 of step 0 fences all waves' Q reads before first Pt overwrite.)

  unsigned short* PtW = &QPt[(size_t)wid * 2304];  // per-wave [2][16][72]

  // precomputed swizzled read offsets (row&7 = (lr+c)&7 for K, lr&7 for V)
  const unsigned char* kbB = KBASE(h) + lr * 128;
  int kofs[3][2];
#pragma unroll
  for (int c = 0; c < 3; ++c)
#pragma unroll
    for (int dh = 0; dh < 2; ++dh)
      kofs[c][dh] = (((((dh << 2) + lg) ^ ((lr + c) & 7)) << 4)) + c * 128;
  const unsigned char* vbB0 = VBASE(0) + lr * 128;
  const unsigned char* vbB1 = VBASE(1) + lr * 128;
  int vofs[2];
#pragma unroll
  for (int kj = 0; kj < 2; ++kj)
    vofs[kj] = ((((kj << 2) + lg) ^ (lr & 7)) << 4);

  float mreg[2] = {-3.0e38f, -3.0e38f};
  float lreg[2] = {0.f, 0.f};
  f32x4 acc[2][2][4] = {};  // [v-head k2][qs][nt(d)]

  for (int s = 0; s < NKS; ++s) {
    // ---- phase 1: write staged K/V regs to LDS (swizzled chunks) ----
    {
      unsigned char* kr0 = KBASE(0) + krow * 128;
      unsigned char* kr1 = KBASE(1) + krow * 128;
      const int ksw = krow & 7;
      *(u16x8*)(kr0 + ((kc0 ^ ksw) << 4)) = kreg[0];
      *(u16x8*)(kr0 + (((kc0 + 1) ^ ksw) << 4)) = kreg[1];
      *(u16x8*)(kr1 + ((kc0 ^ ksw) << 4)) = kreg[2];
      *(u16x8*)(kr1 + (((kc0 + 1) ^ ksw) << 4)) = kreg[3];
      if (tid < 16) {
        const int k2sw = k2r & 7, k2c = tid & 7;
        *(u16x8*)(KBASE(0) + k2r * 128 + ((k2c ^ k2sw) << 4)) = kreg2[0];
        *(u16x8*)(KBASE(1) + k2r * 128 + ((k2c ^ k2sw) << 4)) = kreg2[1];
      }
      unsigned char* vr0 = VBASE(0) + vd * 128;
      unsigned char* vr1 = VBASE(1) + vd * 128;
      const int vsw = vd & 7, vcc = (tid & 3) << 1;
      *(u16x8*)(vr0 + ((vcc ^ vsw) << 4)) = vreg[0];
      *(u16x8*)(vr0 + (((vcc + 1) ^ vsw) << 4)) = vreg[1];
      *(u16x8*)(vr1 + ((vcc ^ vsw) << 4)) = vreg[2];
      *(u16x8*)(vr1 + (((vcc + 1) ^ vsw) << 4)) = vreg[3];
    }
    __syncthreads();  // B1

    // ---- phase 2: issue loads for step s+1 ----
    if (s + 1 < NKS) {
      const int j1 = (s + 1) << 6;
      const int gj = j1 - 1 + krow;
#pragma unroll
      for (int hh = 0; hh < 2; ++hh) {
        kreg[2 * hh] = *(const u16x8*)(Kz + hh * HSTR + (size_t)gj * 64 + kd0);
        kreg[2 * hh + 1] =
            *(const u16x8*)(Kz + hh * HSTR + (size_t)gj * 64 + kd0 + 8);
      }
      if (tid < 16) {
        const int gj2 = j1 - 1 + k2r;
#pragma unroll
        for (int hh = 0; hh < 2; ++hh) {
          u16x8 a = {};
          if (gj2 < N_)
            a = *(const u16x8*)(Kz + hh * HSTR + (size_t)gj2 * 64 + k2d);
          kreg2[hh] = a;
        }
      }
#pragma unroll
      for (int hh = 0; hh < 2; ++hh)
#pragma unroll
        for (int hf = 0; hf < 2; ++hf)
          vreg[2 * hh + hf] = *(const u16x8*)(Vz + hh * HSTR + (size_t)vd * 1024 +
                                              j1 + vc0 + (hf << 3));
    }

    // ---- phase 3: swapped conv-QK^T, K-frag shared across both qs ----
    f32x4 racc[2][4] = {};
    __builtin_amdgcn_s_setprio(1);
#pragma unroll
    for (int c = 0; c < 3; ++c) {
#pragma unroll
      for (int dh = 0; dh < 2; ++dh) {
#pragma unroll
        for (int nt = 0; nt < 4; ++nt) {
          const bf16x8 ak = *(const bf16x8*)(kbB + nt * 2048 + kofs[c][dh]);
          racc[0][nt] = __builtin_amdgcn_mfma_f32_16x16x32_bf16(
              ak, qtf[0][c][dh], racc[0][nt], 0, 0, 0);
          racc[1][nt] = __builtin_amdgcn_mfma_f32_16x16x32_bf16(
              ak, qtf[1][c][dh], racc[1][nt], 0, 0, 0);
        }
      }
    }
    __builtin_amdgcn_s_setprio(0);

    // ---- phase 4: per-lane online softmax (log2 domain, defer-max) ----
    {
      float pmax[2];
#pragma unroll
      for (int qs = 0; qs < 2; ++qs) {
        float pm = fmaxf(fmaxf(racc[qs][0][0], racc[qs][0][1]),
                         fmaxf(racc[qs][0][2], racc[qs][0][3]));
#pragma unroll
        for (int nt = 1; nt < 4; ++nt)
          pm = fmaxf(pm, fmaxf(fmaxf(racc[qs][nt][0], racc[qs][nt][1]),
                               fmaxf(racc[qs][nt][2], racc[qs][nt][3])));
        pm = fmaxf(pm, __shfl_xor(pm, 16));
        pm = fmaxf(pm, __shfl_xor(pm, 32));
        pmax[qs] = pm;
      }
      if (__any((pmax[0] > mreg[0] + 8.f) || (pmax[1] > mreg[1] + 8.f))) {
#pragma unroll
        for (int qs = 0; qs < 2; ++qs) {
          const float mn = fmaxf(mreg[qs], pmax[qs]);
          const float alpha = exp2f(mreg[qs] - mn);
          mreg[qs] = mn;
          lreg[qs] *= alpha;
          float a4[4];
#pragma unroll
          for (int q = 0; q < 4; ++q)
            a4[q] = __shfl(alpha, (lg << 4) | ((lg << 2) + q));
#pragma unroll
          for (int k2 = 0; k2 < 2; ++k2)
#pragma unroll
            for (int nt = 0; nt < 4; ++nt)
#pragma unroll
              for (int q = 0; q < 4; ++q) acc[k2][qs][nt][q] *= a4[q];
        }
      }
#pragma unroll
      for (int qs = 0; qs < 2; ++qs) {
        float rs = 0.f;
#pragma unroll
        for (int nt = 0; nt < 4; ++nt)
#pragma unroll
          for (int q = 0; q < 4; ++q) {
            const float p = exp2f(racc[qs][nt][q] - mreg[qs]);
            racc[qs][nt][q] = p;
            rs += p;
          }
        rs += __shfl_xor(rs, 16);
        rs += __shfl_xor(rs, 32);
        lreg[qs] += rs;
#pragma unroll
        for (int nt = 0; nt < 4; ++nt) {
          ushort4 pw;
          pw.x = f2bf(racc[qs][nt][0]); pw.y = f2bf(racc[qs][nt][1]);
          pw.z = f2bf(racc[qs][nt][2]); pw.w = f2bf(racc[qs][nt][3]);
          *(ushort4*)&PtW[(size_t)qs * 1152 + (size_t)lr * 72 + (nt << 4) +
                          (lg << 2)] = pw;
        }
      }
    }

    // ---- phase 5: PV (both v-heads), V-frag shared across both qs ----
    {
      bf16x8 paf[2][2];
#pragma unroll
      for (int qs = 0; qs < 2; ++qs) {
        paf[qs][0] = *(const bf16x8*)&PtW[(size_t)qs * 1152 + (size_t)lr * 72 + lk];
        paf[qs][1] =
            *(const bf16x8*)&PtW[(size_t)qs * 1152 + (size_t)lr * 72 + 32 + lk];
      }
      __builtin_amdgcn_s_setprio(1);
#pragma unroll
      for (int kj = 0; kj < 2; ++kj)
#pragma unroll
        for (int nt = 0; nt < 4; ++nt) {
          const bf16x8 bva = *(const bf16x8*)(vbB0 + nt * 2048 + vofs[kj]);
          const bf16x8 bvb = *(const bf16x8*)(vbB1 + nt * 2048 + vofs[kj]);
#pragma unroll
          for (int qs = 0; qs < 2; ++qs) {
            acc[0][qs][nt] = __builtin_amdgcn_mfma_f32_16x16x32_bf16(
                paf[qs][kj], bva, acc[0][qs][nt], 0, 0, 0);
            acc[1][qs][nt] = __builtin_amdgcn_mfma_f32_16x16x32_bf16(
                paf[qs][kj], bvb, acc[1][qs][nt], 0, 0, 0);
          }
        }
      __builtin_amdgcn_s_setprio(0);
    }
    __syncthreads();  // B3 (protects K/V LDS for next staging)
  }

  // ---- epilogue: O_k = sum_h hm[h,k]/l_h * A_hk ----
  if (lg == 0) {
    lsum[h * 64 + (mt << 5) + lr] = lreg[0];
    lsum[h * 64 + (mt << 5) + 16 + lr] = lreg[1];
  }
  __syncthreads();

  const float mw0 = hm[(g * 2 + h) * 2 + 0];
  const float mw1 = hm[(g * 2 + h) * 2 + 1];
  float* Os = (float*)smem;  // [2k2][64 rows][68] f32 = 34,816 B (< lsum ofs)
  if (h == 1) {
#pragma unroll
    for (int qs = 0; qs < 2; ++qs)
#pragma unroll
      for (int q = 0; q < 4; ++q) {
        const int row = (mt << 5) + (qs << 4) + (lg << 2) + q;
        const float f0 = mw0 / lsum[64 + row];
        const float f1 = mw1 / lsum[64 + row];
#pragma unroll
        for (int nt = 0; nt < 4; ++nt) {
          Os[(size_t)(0 * 64 + row) * 68 + (nt << 4) + lr] =
              acc[0][qs][nt][q] * f0;
          Os[(size_t)(1 * 64 + row) * 68 + (nt << 4) + lr] =
              acc[1][qs][nt][q] * f1;
        }
      }
  }
  __syncthreads();
  if (h == 0) {
#pragma unroll
    for (int qs = 0; qs < 2; ++qs)
#pragma unroll
      for (int q = 0; q < 4; ++q) {
        const int row = (mt << 5) + (qs << 4) + (lg << 2) + q;
        const int gi = i0 + row;
        const float f0 = mw0 / lsum[row];
        const float f1 = mw1 / lsum[row];
#pragma unroll
        for (int nt = 0; nt < 4; ++nt) {
          const float v0 = acc[0][qs][nt][q] * f0 +
                           Os[(size_t)(0 * 64 + row) * 68 + (nt << 4) + lr];
          const float v1 = acc[1][qs][nt][q] * f1 +
                           Os[(size_t)(1 * 64 + row) * 68 + (nt << 4) + lr];
          pvout[(size_t)(bb * N_ + gi) * C_ + (2 * g + 0) * 64 + (nt << 4) +
                lr] = f2bf(v0);
          pvout[(size_t)(bb * N_ + gi) * C_ + (2 * g + 1) * 64 + (nt << 4) +
                lr] = f2bf(v1);
        }
      }
  }
#undef KBASE
#undef VBASE
}

extern "C" void kernel_launch(void* const* d_in, const int* in_sizes, int n_in,
                              void* d_out, int out_size, void* d_ws, size_t ws_size,
                              hipStream_t stream) {
  const float* query = (const float*)d_in[0];
  const float* key   = (const float*)d_in[1];
  const float* value = (const float*)d_in[2];
  const float* Wq = (const float*)d_in[3];
  const float* bq = (const float*)d_in[4];
  const float* Wk = (const float*)d_in[5];
  const float* bk = (const float*)d_in[6];
  const float* Wv = (const float*)d_in[7];
  const float* bv = (const float*)d_in[8];
  const float* cw = (const float*)d_in[9];
  const float* hm = (const float*)d_in[10];
  const float* Wo = (const float*)d_in[11];
  const float* bo = (const float*)d_in[12];
  float* out = (float*)d_out;

  char* ws = (char*)d_ws;
  const size_t SZ_BF = (size_t)B_ * H_ * N_ * 64 * 2;  // 12,582,912 B
  unsigned short* Qb = (unsigned short*)ws;
  unsigned short* Kb = (unsigned short*)(ws + SZ_BF);
  unsigned short* Vt = (unsigned short*)(ws + 2 * SZ_BF);   // (B,H,D,N)
  unsigned short* pvb = (unsigned short*)(ws + 3 * SZ_BF);  // bf16 (B,N,C)
  unsigned short* Wb = (unsigned short*)(ws + 4 * SZ_BF);   // Wq,Wk,Wv,Wo bf16

  const dim3 blk(256);
  cvtW<<<dim3(288, 4), blk, 0, stream>>>(Wq, Wk, Wv, Wo, Wb);
  proj3<<<dim3(1152), blk, 0, stream>>>(query, key, value, Wb, bq, bk, bv, Qb,
                                        Kb, Vt);
  fused_attn<<<dim3(768), blk, 0, stream>>>(Qb, Kb, Vt, cw, hm, pvb);
  oproj<<<dim3(384), blk, 0, stream>>>(pvb, Wb, bo, out);
}